// Round 6
// baseline (118.233 us; speedup 1.0000x reference)
//
#include <hip/hip_runtime.h>
#include <math.h>

static constexpr int B_ = 32;
static constexpr int RES_ = 50;
static constexpr int F_ = 256;              // fine grid
static constexpr int TROWS = 56;            // padded T rows (8 groups x 7)
#define NF (1.0f/(2.0f*0.05f*0.05f + 1e-8f))

// ---------------------------------------------------------------------------
// K0: Gaussian slot-table gtab[cx][64]; slot s = 8*g + k maps to grid row
//     i = 7*g + k (k<7, i<50); other slots 0. 64 KB, read wave-uniform.
// ---------------------------------------------------------------------------
__global__ void k_tables(float* __restrict__ gtab) {
    int cx = blockIdx.x;                    // 0..255
    int s  = threadIdx.x;                   // 0..63
    int g = s >> 3, k = s & 7;
    int i = g * 7 + k;
    float v = 0.0f;
    if (k < 7 && i < RES_) {
        float d = (float)i * (1.0f / 49.0f) - (float)cx * (1.0f / 255.0f);
        v = __expf(-d * d * NF);
    }
    gtab[cx * 64 + s] = v;
}

// ---------------------------------------------------------------------------
// K1: FUSED splat + conv1.
//     Grid 256 = (seg:2, p:4, b:32), id = seg*128 + p*32 + b  (id%8 == b%8:
//     both seg-halves of a (p,b) chunk on one XCD -> L2-shared point reads).
//     Phase A: zero 256x128 fp32 tile (128 KB LDS).
//     Phase B: scan chunk (8 float4/thread, register-batched), bilinear
//              LDS atomics into the cy half this block owns.
//     Phase C: T_part[p][b][i][seg*128+cy] = sum_cx gtab[cx][i]*tile[cx][cy]
//              (8 row-groups x 7 rows; wave-uniform table loads; plain stores)
// ---------------------------------------------------------------------------
__global__ void __launch_bounds__(1024, 1) k_fused(const float4* __restrict__ pts,
                                                   const float* __restrict__ gtab,
                                                   float* __restrict__ T) {
    extern __shared__ float tile[];         // 256*128 floats = 128 KB
    int id  = blockIdx.x;
    int b   = id & 31;
    int p   = (id >> 5) & 3;
    int seg = id >> 7;                      // 0..1

    // --- Phase A: zero tile (float4) ---
    float4* t4 = (float4*)tile;
    for (int t = threadIdx.x; t < 8192; t += 1024)
        t4[t] = make_float4(0.f, 0.f, 0.f, 0.f);
    __syncthreads();

    // --- Phase B: scan + splat ---
    const float4* src = pts + ((size_t)b << 15) + ((size_t)p << 13);
    float4 q[8];
#pragma unroll
    for (int r = 0; r < 8; r++) q[r] = src[threadIdx.x + (r << 10)];

    int ylo = seg << 7;
#pragma unroll
    for (int r = 0; r < 8; r++) {
#pragma unroll
        for (int h = 0; h < 2; h++) {
            float bx = h ? q[r].z : q[r].x;
            float dy = h ? q[r].w : q[r].y;
            float pers = fminf(fabsf(dy - bx), 10.0f);
            float wgt = pers * pers;
            float fx = fminf(fmaxf(bx * 255.0f, 0.0f), 255.0f);
            float fy = fminf(fmaxf(dy * 255.0f, 0.0f), 255.0f);
            int ix = (int)fx; if (ix > 254) ix = 254;
            int iy = (int)fy; if (iy > 254) iy = 254;
            float ax = fx - (float)ix;
            float ay = fy - (float)iy;
            int cy0 = iy - ylo;
            float wx0 = wgt * (1.0f - ax), wx1 = wgt * ax;
            int o0 = (ix << 7) + cy0;
            if ((unsigned)cy0 < 128u) {
                float a0 = 1.0f - ay;
                atomicAdd(&tile[o0],       wx0 * a0);
                atomicAdd(&tile[o0 + 128], wx1 * a0);
            }
            if ((unsigned)(cy0 + 1) < 128u) {
                atomicAdd(&tile[o0 + 1],   wx0 * ay);
                atomicAdd(&tile[o0 + 129], wx1 * ay);
            }
        }
    }
    __syncthreads();

    // --- Phase C: contract tile against Gaussian table ---
    int tx = threadIdx.x & 127;             // cy-local (lanes contiguous)
    int ty = threadIdx.x >> 7;              // row group 0..7 (wave-uniform)

    float acc[7];
#pragma unroll
    for (int k = 0; k < 7; k++) acc[k] = 0.0f;

    const float* gp = gtab + (ty << 3);
#pragma unroll 4
    for (int cx = 0; cx < 256; cx++) {
        float hv = tile[(cx << 7) + tx];
        float4 g0 = *(const float4*)(gp + (cx << 6));
        float4 g1 = *(const float4*)(gp + (cx << 6) + 4);
        acc[0] += g0.x * hv;  acc[1] += g0.y * hv;
        acc[2] += g0.z * hv;  acc[3] += g0.w * hv;
        acc[4] += g1.x * hv;  acc[5] += g1.y * hv;
        acc[6] += g1.z * hv;                       // slot 7 is zero-padding
    }

    float* Tp = T + ((size_t)p * B_ + b) * (TROWS * F_)
                  + (size_t)(ty * 7) * F_ + ylo + tx;
#pragma unroll
    for (int k = 0; k < 7; k++) Tp[(size_t)k * F_] = acc[k];
}

// ---------------------------------------------------------------------------
// K2: out[b][i][j] = sum_cy (sum_p T_part[p][b][i][cy]) * G[cy][j]
//     Grid 128 = (q:4, b:32), id%8==b%8. Gaussian inline; parts summed
//     during LDS staging; 4-wave cy-split + LDS tree reduce.
// ---------------------------------------------------------------------------
__global__ void __launch_bounds__(256) k_conv2(const float* __restrict__ T,
                                               float* __restrict__ out) {
    __shared__ float sT[13 * 256];          // 13 KB, reused as red[4][13][64]
    int b = blockIdx.x & 31;
    int q = blockIdx.x >> 5;

    const size_t TP = (size_t)B_ * TROWS * F_;
    const float* Tq = T + (size_t)b * (TROWS * F_) + (size_t)(q * 13) * F_;
    for (int t = threadIdx.x; t < 13 * 256; t += 256)
        sT[t] = Tq[t] + Tq[TP + t] + Tq[2 * TP + t] + Tq[3 * TP + t];
    __syncthreads();

    int j = threadIdx.x & 63;
    int w = threadIdx.x >> 6;
    int jc = j < RES_ ? j : RES_ - 1;
    float xj = (float)jc * (1.0f / 49.0f);

    float acc[13];
#pragma unroll
    for (int k = 0; k < 13; k++) acc[k] = 0.0f;

    int cyb = w * 64;
#pragma unroll 4
    for (int c = 0; c < 64; c++) {
        float d = xj - (float)(cyb + c) * (1.0f / 255.0f);
        float g = __expf(-d * d * NF);
#pragma unroll
        for (int k = 0; k < 13; k++) acc[k] += sT[k * 256 + cyb + c] * g;
    }
    __syncthreads();

#pragma unroll
    for (int k = 0; k < 13; k++) sT[(w * 13 + k) * 64 + j] = acc[k];
    __syncthreads();

    for (int t = threadIdx.x; t < 13 * 64; t += 256) {
        int k = t >> 6, jj = t & 63;
        int i = q * 13 + k;
        if (i < RES_ && jj < RES_) {
            float s = sT[(0 * 13 + k) * 64 + jj] + sT[(1 * 13 + k) * 64 + jj]
                    + sT[(2 * 13 + k) * 64 + jj] + sT[(3 * 13 + k) * 64 + jj];
            out[((size_t)b * RES_ + i) * RES_ + jj] = s;
        }
    }
}

// ---------------------------------------------------------------------------
extern "C" void kernel_launch(void* const* d_in, const int* in_sizes, int n_in,
                              void* d_out, int out_size, void* d_ws, size_t ws_size,
                              hipStream_t stream) {
    const float4* pts = (const float4*)d_in[0];
    float* ws = (float*)d_ws;
    float* out = (float*)d_out;

    float* gtab = ws;                         // 256*64 = 16,384 floats (64 KB)
    float* T    = gtab + F_ * 64;             // 4*32*56*256 = 1,835,008 floats (7.3 MB)
                                              // total ~7.4 MB (ws >= 43.7 MB proven R1)

    // allow 128 KB dynamic LDS (no-op if already permitted; deterministic)
    hipFuncSetAttribute((const void*)k_fused,
                        hipFuncAttributeMaxDynamicSharedMemorySize, 131072);

    k_tables<<<F_, 64, 0, stream>>>(gtab);
    k_fused<<<256, 1024, 131072, stream>>>(pts, gtab, T);
    k_conv2<<<128, 256, 0, stream>>>(T, out);
}